// Round 20
// baseline (168.861 us; speedup 1.0000x reference)
//
#include <hip/hip_runtime.h>
#include <hip/hip_bf16.h>

#define BH_N 16
#define SEQ 2048
#define DH 128
#define PSTR 2056   // strip row stride in shorts (2048 + 8: keeps 16B row alignment)

typedef __attribute__((ext_vector_type(8))) short bf16x8;
typedef __attribute__((ext_vector_type(4))) float f32x4;

__device__ __forceinline__ short f2bf(float x) {
    union { __hip_bfloat16 b; short s; } u;
    u.b = __float2bfloat16(x);
    return u.s;
}
__device__ __forceinline__ float bf2f(unsigned short s) {
    union { unsigned int u; float f; } v;
    v.u = ((unsigned int)s) << 16;
    return v.f;
}

// ---------- prep: K -> bf16 [bh][key][d]; V -> bf16 transposed [bh][d][key] ----------
__global__ __launch_bounds__(256) void prep_kv(
    const float* __restrict__ kp, const float* __restrict__ vp,
    unsigned short* __restrict__ Kb, unsigned short* __restrict__ Vt)
{
    const int tid  = threadIdx.x;
    const int kb64 = blockIdx.x * 64;
    const int bh   = blockIdx.y;
    const float* Ksrc = kp + ((size_t)bh * SEQ + kb64) * DH;
    const float* Vsrc = vp + ((size_t)bh * SEQ + kb64) * DH;
    unsigned short* Kdst = Kb + ((size_t)bh * SEQ + kb64) * DH;
    unsigned short* Vdst = Vt + (size_t)bh * DH * SEQ + kb64;

    #pragma unroll
    for (int i = 0; i < 8; ++i) {
        const int f4 = i * 256 + tid;
        const float4 kv = *(const float4*)(Ksrc + (size_t)f4 * 4);
        ushort4 o;
        o.x = (unsigned short)f2bf(kv.x); o.y = (unsigned short)f2bf(kv.y);
        o.z = (unsigned short)f2bf(kv.z); o.w = (unsigned short)f2bf(kv.w);
        *(ushort4*)(Kdst + (size_t)f4 * 4) = o;
    }
    const int key   = tid & 63;
    const int dbase = (tid >> 6) * 4;
    #pragma unroll
    for (int j = 0; j < 8; ++j) {
        const int d0 = dbase + j * 16;
        const float4 vv = *(const float4*)(Vsrc + (size_t)key * DH + d0);
        Vdst[(size_t)(d0 + 0) * SEQ + key] = (unsigned short)f2bf(vv.x);
        Vdst[(size_t)(d0 + 1) * SEQ + key] = (unsigned short)f2bf(vv.y);
        Vdst[(size_t)(d0 + 2) * SEQ + key] = (unsigned short)f2bf(vv.z);
        Vdst[(size_t)(d0 + 3) * SEQ + key] = (unsigned short)f2bf(vv.w);
    }
}

#define LOADK4(K0, K1, K2, K3, KEYBASE) do {                                   \
    const unsigned short* kr_ = Kbh + (size_t)((KEYBASE) + c16) * DH + g * 8;  \
    K0 = *(const bf16x8*)(kr_);                                                \
    K1 = *(const bf16x8*)(kr_ + 32);                                           \
    K2 = *(const bf16x8*)(kr_ + 64);                                           \
    K3 = *(const bf16x8*)(kr_ + 96);                                           \
} while (0)

// sweep-1 tile: 2 independent MFMA accumulator chains (halved dep latency),
// exp (unnormalized), rowsum accumulate, strip write
#define SW1(K0, K1, K2, K3, KEYBASE) do {                                      \
    f32x4 accA_ = {0.f, 0.f, 0.f, 0.f};                                        \
    f32x4 accB_ = {0.f, 0.f, 0.f, 0.f};                                        \
    accA_ = __builtin_amdgcn_mfma_f32_16x16x32_bf16(qf[0], K0, accA_, 0, 0, 0);\
    accB_ = __builtin_amdgcn_mfma_f32_16x16x32_bf16(qf[1], K1, accB_, 0, 0, 0);\
    accA_ = __builtin_amdgcn_mfma_f32_16x16x32_bf16(qf[2], K2, accA_, 0, 0, 0);\
    accB_ = __builtin_amdgcn_mfma_f32_16x16x32_bf16(qf[3], K3, accB_, 0, 0, 0);\
    accA_ += accB_;                                                            \
    const int key_ = (KEYBASE) + c16;                                          \
    const int qr_  = qw + g * 4;                                               \
    const float p0_ = (key_ <= qr_ + 0) ? __expf(accA_[0]) : 0.f;              \
    const float p1_ = (key_ <= qr_ + 1) ? __expf(accA_[1]) : 0.f;              \
    const float p2_ = (key_ <= qr_ + 2) ? __expf(accA_[2]) : 0.f;              \
    const float p3_ = (key_ <= qr_ + 3) ? __expf(accA_[3]) : 0.f;              \
    lsr[0] += p0_; lsr[1] += p1_; lsr[2] += p2_; lsr[3] += p3_;                \
    unsigned short* pq_ = &strip[g * 4][0] + key_;                             \
    pq_[0]        = (unsigned short)f2bf(p0_);                                 \
    pq_[PSTR]     = (unsigned short)f2bf(p1_);                                 \
    pq_[2 * PSTR] = (unsigned short)f2bf(p2_);                                 \
    pq_[3 * PSTR] = (unsigned short)f2bf(p3_);                                 \
} while (0)

#define LOADV8(V0,V1,V2,V3,V4,V5,V6,V7, KEYOFF) do {                           \
    const unsigned short* vb_ = Vbh + (size_t)c16 * SEQ + (KEYOFF) + g * 8;    \
    V0 = *(const bf16x8*)(vb_);                                                \
    V1 = *(const bf16x8*)(vb_ + 16 * SEQ);                                     \
    V2 = *(const bf16x8*)(vb_ + 32 * SEQ);                                     \
    V3 = *(const bf16x8*)(vb_ + 48 * SEQ);                                     \
    V4 = *(const bf16x8*)(vb_ + 64 * SEQ);                                     \
    V5 = *(const bf16x8*)(vb_ + 80 * SEQ);                                     \
    V6 = *(const bf16x8*)(vb_ + 96 * SEQ);                                     \
    V7 = *(const bf16x8*)(vb_ + 112 * SEQ);                                    \
} while (0)

#define PV8(PA, V0,V1,V2,V3,V4,V5,V6,V7) do {                                  \
    oacc[0] = __builtin_amdgcn_mfma_f32_16x16x32_bf16(PA, V0, oacc[0], 0, 0, 0); \
    oacc[1] = __builtin_amdgcn_mfma_f32_16x16x32_bf16(PA, V1, oacc[1], 0, 0, 0); \
    oacc[2] = __builtin_amdgcn_mfma_f32_16x16x32_bf16(PA, V2, oacc[2], 0, 0, 0); \
    oacc[3] = __builtin_amdgcn_mfma_f32_16x16x32_bf16(PA, V3, oacc[3], 0, 0, 0); \
    oacc[4] = __builtin_amdgcn_mfma_f32_16x16x32_bf16(PA, V4, oacc[4], 0, 0, 0); \
    oacc[5] = __builtin_amdgcn_mfma_f32_16x16x32_bf16(PA, V5, oacc[5], 0, 0, 0); \
    oacc[6] = __builtin_amdgcn_mfma_f32_16x16x32_bf16(PA, V6, oacc[6], 0, 0, 0); \
    oacc[7] = __builtin_amdgcn_mfma_f32_16x16x32_bf16(PA, V7, oacc[7], 0, 0, 0); \
} while (0)

// ---------- main: round-19 + dependency-chain attack ----------
// (1) sweep-1 K prefetch 4-deep (VGPR 56 -> ~110, under the 128 cap; FETCH is
//     the spill canary), (2) split MFMA accumulator chains, (3) sweep-2 V
//     refilled cross-iteration (latency hidden under a full PV iteration).
__global__ __launch_bounds__(512, 4) void attn_main(
    const float* __restrict__ qp, const unsigned short* __restrict__ Kb,
    const unsigned short* __restrict__ Vt, float* __restrict__ outO,
    float* __restrict__ outA)
{
    __shared__ float lspart[8][16];
    __shared__ float lrec[16];
    __shared__ float Osh[16][132];
    __shared__ __align__(16) unsigned short strip[16][PSTR];   // 65,792 B

    const int b   = blockIdx.x;            // 0..2047
    const int j   = b & 7;                 // XCD (validated: FETCH 38MB w/, 68MB w/o)
    const int idx = b >> 3;                // 0..255
    const int bh  = 2 * j + (idx & 1);
    const int qt  = 127 - (idx >> 1);      // heavy first (LPT)
    const int qw  = qt * 16;
    const size_t qbase = (size_t)bh * SEQ + qw;

    const int tid  = threadIdx.x;
    const int wv   = tid >> 6;
    const int lane = tid & 63;
    const int c16  = lane & 15;
    const int g    = lane >> 4;
    const float invT = 0.08838834764831845f;   // 1/sqrt(128)

    const unsigned short* Kbh = Kb + (size_t)bh * SEQ * DH;
    const unsigned short* Vbh = Vt + (size_t)bh * DH * SEQ;

    // ---- Q fragments: A[row=c16][k=32c+8g+j], pre-scaled ----
    bf16x8 qf[4];
    {
        const float* qrow = qp + (qbase + c16) * DH + g * 8;
        #pragma unroll
        for (int c = 0; c < 4; ++c) {
            const float4 a = *(const float4*)(qrow + c * 32);
            const float4 bq = *(const float4*)(qrow + c * 32 + 4);
            bf16x8 f;
            f[0] = f2bf(a.x * invT);  f[1] = f2bf(a.y * invT);
            f[2] = f2bf(a.z * invT);  f[3] = f2bf(a.w * invT);
            f[4] = f2bf(bq.x * invT); f[5] = f2bf(bq.y * invT);
            f[6] = f2bf(bq.z * invT); f[7] = f2bf(bq.w * invT);
            qf[c] = f;
        }
    }

    // ---- sweep 1: QK^T once, P' -> strip, rowsums; stride-8, 4-deep K prefetch ----
    // NOTE: steady-loop prefetches may read up to ~230KB past this bh's K region;
    // they stay inside ws (Kb is followed by Vt) and are never consumed.
    float lsr[4] = {0.f, 0.f, 0.f, 0.f};
    const int n16 = qt + 1;
    {
        bf16x8 kA0,kA1,kA2,kA3, kB0,kB1,kB2,kB3, kC0,kC1,kC2,kC3, kD0,kD1,kD2,kD3;
        int t = wv;
        if (t < n16)      LOADK4(kA0,kA1,kA2,kA3, t << 4);
        if (t + 8 < n16)  LOADK4(kB0,kB1,kB2,kB3, (t + 8) << 4);
        if (t + 16 < n16) LOADK4(kC0,kC1,kC2,kC3, (t + 16) << 4);
        if (t + 24 < n16) LOADK4(kD0,kD1,kD2,kD3, (t + 24) << 4);
        for (; t + 32 < n16; t += 32) {
            SW1(kA0,kA1,kA2,kA3, t << 4);        LOADK4(kA0,kA1,kA2,kA3, (t + 32) << 4);
            SW1(kB0,kB1,kB2,kB3, (t + 8) << 4);  LOADK4(kB0,kB1,kB2,kB3, (t + 40) << 4);
            SW1(kC0,kC1,kC2,kC3, (t + 16) << 4); LOADK4(kC0,kC1,kC2,kC3, (t + 48) << 4);
            SW1(kD0,kD1,kD2,kD3, (t + 24) << 4); LOADK4(kD0,kD1,kD2,kD3, (t + 56) << 4);
        }
        if (t < n16)      SW1(kA0,kA1,kA2,kA3, t << 4);
        if (t + 8 < n16)  SW1(kB0,kB1,kB2,kB3, (t + 8) << 4);
        if (t + 16 < n16) SW1(kC0,kC1,kC2,kC3, (t + 16) << 4);
        if (t + 24 < n16) SW1(kD0,kD1,kD2,kD3, (t + 24) << 4);
    }
    #pragma unroll
    for (int r = 0; r < 4; ++r) {
        float s = lsr[r];
        #pragma unroll
        for (int m = 1; m < 16; m <<= 1) s += __shfl_xor(s, m);
        lsr[r] = s;
    }
    if (c16 == 0) {
        #pragma unroll
        for (int r = 0; r < 4; ++r) lspart[wv][g * 4 + r] = lsr[r];
    }
    __syncthreads();
    float li[4];
    #pragma unroll
    for (int r = 0; r < 4; ++r) {
        float s = 0.f;
        #pragma unroll
        for (int w = 0; w < 8; ++w) s += lspart[w][g * 4 + r];
        li[r] = 1.f / s;
    }
    const int ns = (qw + 79) >> 6;        // 64-key super-tiles covering keys <= qw+15
    if (wv == 0 && c16 == 0) {
        #pragma unroll
        for (int r = 0; r < 4; ++r) lrec[g * 4 + r] = li[r];
    }
    // zero strip gap cols [n16*16, ns*64)
    {
        const int row = tid >> 5;
        for (int c = n16 * 16 + (tid & 31); c < ns * 64; c += 32) strip[row][c] = 0;
    }
    __syncthreads();

    // ---- sweep 2: PV only; V refilled cross-iteration (latency hidden) ----
    f32x4 oacc[8];
    #pragma unroll
    for (int d = 0; d < 8; ++d) oacc[d] = (f32x4){0.f, 0.f, 0.f, 0.f};

    {
        bf16x8 va0, va1, va2, va3, va4, va5, va6, va7;
        bf16x8 vb0, vb1, vb2, vb3, vb4, vb5, vb6, vb7;
        int S = wv;
        if (S < ns) {
            LOADV8(va0,va1,va2,va3,va4,va5,va6,va7, S << 6);
            LOADV8(vb0,vb1,vb2,vb3,vb4,vb5,vb6,vb7, (S << 6) + 32);
        }
        for (; S < ns; S += 8) {
            const int KB = S << 6;
            {
                const bf16x8 pa = *(const bf16x8*)(&strip[c16][KB + g * 8]);
                PV8(pa, va0,va1,va2,va3,va4,va5,va6,va7);
            }
            if (S + 8 < ns) LOADV8(va0,va1,va2,va3,va4,va5,va6,va7, (S + 8) << 6);
            {
                const bf16x8 pa = *(const bf16x8*)(&strip[c16][KB + 32 + g * 8]);
                PV8(pa, vb0,vb1,vb2,vb3,vb4,vb5,vb6,vb7);
            }
            if (S + 8 < ns) LOADV8(vb0,vb1,vb2,vb3,vb4,vb5,vb6,vb7, ((S + 8) << 6) + 32);
        }
    }

    // ---- store pass: each wave streams 2 whole rows [0, SEQ) with NT stores ----
    {
        const int valid = ns * 64;
        #pragma unroll
        for (int rr = 0; rr < 2; ++rr) {
            const int row = wv * 2 + rr;
            const float lr = lrec[row];
            float* orow = outA + (qbase + row) * SEQ;
            const unsigned short* srow = &strip[row][0];
            for (int c = lane * 4; c < SEQ; c += 256) {
                f32x4 w;
                if (c < valid) {
                    w[0] = bf2f(srow[c + 0]) * lr;
                    w[1] = bf2f(srow[c + 1]) * lr;
                    w[2] = bf2f(srow[c + 2]) * lr;
                    w[3] = bf2f(srow[c + 3]) * lr;
                } else {
                    w[0] = 0.f; w[1] = 0.f; w[2] = 0.f; w[3] = 0.f;
                }
                __builtin_nontemporal_store(w, (f32x4*)(orow + c));
            }
        }
    }

    // ---- O: scale by li, cross-wave reduce in LDS (serial) ----
    for (int wp = 0; wp < 8; ++wp) {
        if (wv == wp) {
            #pragma unroll
            for (int dt = 0; dt < 8; ++dt) {
                #pragma unroll
                for (int r = 0; r < 4; ++r) {
                    const float val = oacc[dt][r] * li[r];
                    if (wp == 0) Osh[g * 4 + r][dt * 16 + c16]  = val;
                    else         Osh[g * 4 + r][dt * 16 + c16] += val;
                }
            }
        }
        __syncthreads();
    }
    {
        const int r  = tid >> 5;
        const int d0 = (tid & 31) * 4;
        float4 o;
        o.x = Osh[r][d0 + 0]; o.y = Osh[r][d0 + 1];
        o.z = Osh[r][d0 + 2]; o.w = Osh[r][d0 + 3];
        *(float4*)(outO + (qbase + r) * DH + d0) = o;
    }
}

// ---------- fallback (used only if ws too small) ----------
__global__ __launch_bounds__(256) void attn_fallback(
    const float* __restrict__ qp, const float* __restrict__ kp,
    const float* __restrict__ vp, float* __restrict__ outO,
    float* __restrict__ outA)
{
    const int qt   = blockIdx.x;
    const int bh   = blockIdx.y;
    const int wv   = threadIdx.x >> 6;
    const int lane = threadIdx.x & 63;
    const int c16  = lane & 15;
    const int g    = lane >> 4;
    const int qw = qt * 64 + wv * 16;
    const size_t qbase = (size_t)bh * SEQ + qw;
    const float invT = 0.08838834764831845f;

    bf16x8 qf[4];
    {
        const float* qrow = qp + (qbase + c16) * DH + g * 8;
        #pragma unroll
        for (int c = 0; c < 4; ++c) {
            const float4 a = *(const float4*)(qrow + c * 32);
            const float4 bq = *(const float4*)(qrow + c * 32 + 4);
            bf16x8 f;
            f[0] = f2bf(a.x * invT);  f[1] = f2bf(a.y * invT);
            f[2] = f2bf(a.z * invT);  f[3] = f2bf(a.w * invT);
            f[4] = f2bf(bq.x * invT); f[5] = f2bf(bq.y * invT);
            f[6] = f2bf(bq.z * invT); f[7] = f2bf(bq.w * invT);
            qf[c] = f;
        }
    }
    const float* kbase = kp + (size_t)bh * SEQ * DH;
    const float* vbase = vp + (size_t)bh * SEQ * DH;

    float ls0 = 0.f, ls1 = 0.f, ls2 = 0.f, ls3 = 0.f;
    const int nkt16 = (qw + 16) >> 4;
    for (int t = 0; t < nkt16; ++t) {
        const int kb = t << 4;
        const float* krow = kbase + (size_t)(kb + c16) * DH + g * 8;
        f32x4 acc = {0.f, 0.f, 0.f, 0.f};
        #pragma unroll
        for (int c = 0; c < 4; ++c) {
            const float4 a = *(const float4*)(krow + c * 32);
            const float4 bq = *(const float4*)(krow + c * 32 + 4);
            bf16x8 f;
            f[0] = f2bf(a.x);  f[1] = f2bf(a.y);  f[2] = f2bf(a.z);  f[3] = f2bf(a.w);
            f[4] = f2bf(bq.x); f[5] = f2bf(bq.y); f[6] = f2bf(bq.z); f[7] = f2bf(bq.w);
            acc = __builtin_amdgcn_mfma_f32_16x16x32_bf16(qf[c], f, acc, 0, 0, 0);
        }
        const int key = kb + c16;
        const int qr  = qw + g * 4;
        if (key <= qr + 0) ls0 += __expf(acc[0]);
        if (key <= qr + 1) ls1 += __expf(acc[1]);
        if (key <= qr + 2) ls2 += __expf(acc[2]);
        if (key <= qr + 3) ls3 += __expf(acc[3]);
    }
    #pragma unroll
    for (int m = 1; m < 16; m <<= 1) {
        ls0 += __shfl_xor(ls0, m);
        ls1 += __shfl_xor(ls1, m);
        ls2 += __shfl_xor(ls2, m);
        ls3 += __shfl_xor(ls3, m);
    }
    const float li0 = 1.f / ls0, li1 = 1.f / ls1, li2 = 1.f / ls2, li3 = 1.f / ls3;

    __shared__ __align__(16) short ptileF[4][16][32];
    f32x4 oacc[8];
    #pragma unroll
    for (int d = 0; d < 8; ++d) oacc[d] = (f32x4){0.f, 0.f, 0.f, 0.f};

    const int n32 = (qw + 47) >> 5;
    for (int t = 0; t < n32; ++t) {
        const int kb32 = t << 5;
        #pragma unroll
        for (int h = 0; h < 2; ++h) {
            const int kb = kb32 + h * 16;
            const float* krow = kbase + (size_t)(kb + c16) * DH + g * 8;
            f32x4 acc = {0.f, 0.f, 0.f, 0.f};
            #pragma unroll
            for (int c = 0; c < 4; ++c) {
                const float4 a = *(const float4*)(krow + c * 32);
                const float4 bq = *(const float4*)(krow + c * 32 + 4);
                bf16x8 f;
                f[0] = f2bf(a.x);  f[1] = f2bf(a.y);  f[2] = f2bf(a.z);  f[3] = f2bf(a.w);
                f[4] = f2bf(bq.x); f[5] = f2bf(bq.y); f[6] = f2bf(bq.z); f[7] = f2bf(bq.w);
                acc = __builtin_amdgcn_mfma_f32_16x16x32_bf16(qf[c], f, acc, 0, 0, 0);
            }
            const int key = kb + c16;
            const int qr  = qw + g * 4;
            const float p0 = (key <= qr + 0) ? __expf(acc[0]) * li0 : 0.f;
            const float p1 = (key <= qr + 1) ? __expf(acc[1]) * li1 : 0.f;
            const float p2 = (key <= qr + 2) ? __expf(acc[2]) * li2 : 0.f;
            const float p3 = (key <= qr + 3) ? __expf(acc[3]) * li3 : 0.f;
            outA[(qbase + g * 4 + 0) * SEQ + kb + c16] = p0;
            outA[(qbase + g * 4 + 1) * SEQ + kb + c16] = p1;
            outA[(qbase + g * 4 + 2) * SEQ + kb + c16] = p2;
            outA[(qbase + g * 4 + 3) * SEQ + kb + c16] = p3;
            ptileF[wv][g * 4 + 0][h * 16 + c16] = f2bf(p0);
            ptileF[wv][g * 4 + 1][h * 16 + c16] = f2bf(p1);
            ptileF[wv][g * 4 + 2][h * 16 + c16] = f2bf(p2);
            ptileF[wv][g * 4 + 3][h * 16 + c16] = f2bf(p3);
        }
        bf16x8 pa = *(bf16x8*)&ptileF[wv][c16][g * 8];
        #pragma unroll
        for (int dt = 0; dt < 8; ++dt) {
            const float* vcol = vbase + (size_t)(kb32 + g * 8) * DH + dt * 16 + c16;
            bf16x8 vf;
            #pragma unroll
            for (int i = 0; i < 8; ++i) vf[i] = f2bf(vcol[(size_t)i * DH]);
            oacc[dt] = __builtin_amdgcn_mfma_f32_16x16x32_bf16(pa, vf, oacc[dt], 0, 0, 0);
        }
    }
    {
        const float4 z4 = {0.f, 0.f, 0.f, 0.f};
        float* zrow = outA + (qbase + (lane >> 2)) * SEQ;
        for (int c = n32 * 32 + (lane & 3) * 8; c < SEQ; c += 32) {
            *(float4*)(zrow + c)     = z4;
            *(float4*)(zrow + c + 4) = z4;
        }
    }
    #pragma unroll
    for (int dt = 0; dt < 8; ++dt) {
        #pragma unroll
        for (int r = 0; r < 4; ++r) {
            outO[(qbase + g * 4 + r) * DH + dt * 16 + c16] = oacc[dt][r];
        }
    }
}

extern "C" void kernel_launch(void* const* d_in, const int* in_sizes, int n_in,
                              void* d_out, int out_size, void* d_ws, size_t ws_size,
                              hipStream_t stream) {
    (void)in_sizes; (void)n_in; (void)out_size;
    const float* q = (const float*)d_in[0];
    const float* k = (const float*)d_in[1];
    const float* v = (const float*)d_in[2];
    float* outO = (float*)d_out;                   // [BH, S, D] f32
    float* outA = outO + (size_t)BH_N * SEQ * DH;  // [BH, S, S] f32

    const size_t need = (size_t)BH_N * SEQ * DH * sizeof(unsigned short) * 2;  // Kb + Vt
    if (ws_size >= need) {
        unsigned short* Kb = (unsigned short*)d_ws;
        unsigned short* Vt = Kb + (size_t)BH_N * SEQ * DH;
        prep_kv<<<dim3(SEQ / 64, BH_N), 256, 0, stream>>>(k, v, Kb, Vt);
        attn_main<<<dim3(2048), 512, 0, stream>>>(q, Kb, Vt, outO, outA);
    } else {
        attn_fallback<<<dim3(SEQ / 64, BH_N), 256, 0, stream>>>(q, k, v, outO, outA);
    }
}

// Round 21
// 164.208 us; speedup vs baseline: 1.0283x; 1.0283x over previous
//
#include <hip/hip_runtime.h>
#include <hip/hip_bf16.h>

#define BH_N 16
#define SEQ 2048
#define DH 128
#define PSTR 2056   // strip row stride in shorts (2048 + 8: keeps 16B row alignment)

typedef __attribute__((ext_vector_type(8))) short bf16x8;
typedef __attribute__((ext_vector_type(4))) float f32x4;

__device__ __forceinline__ short f2bf(float x) {
    union { __hip_bfloat16 b; short s; } u;
    u.b = __float2bfloat16(x);
    return u.s;
}
__device__ __forceinline__ float bf2f(unsigned short s) {
    union { unsigned int u; float f; } v;
    v.u = ((unsigned int)s) << 16;
    return v.f;
}

// ---------- prep: K -> bf16 [bh][key][d]; V -> bf16 transposed [bh][d][key] ----------
__global__ __launch_bounds__(256) void prep_kv(
    const float* __restrict__ kp, const float* __restrict__ vp,
    unsigned short* __restrict__ Kb, unsigned short* __restrict__ Vt)
{
    const int tid  = threadIdx.x;
    const int kb64 = blockIdx.x * 64;
    const int bh   = blockIdx.y;
    const float* Ksrc = kp + ((size_t)bh * SEQ + kb64) * DH;
    const float* Vsrc = vp + ((size_t)bh * SEQ + kb64) * DH;
    unsigned short* Kdst = Kb + ((size_t)bh * SEQ + kb64) * DH;
    unsigned short* Vdst = Vt + (size_t)bh * DH * SEQ + kb64;

    #pragma unroll
    for (int i = 0; i < 8; ++i) {
        const int f4 = i * 256 + tid;
        const float4 kv = *(const float4*)(Ksrc + (size_t)f4 * 4);
        ushort4 o;
        o.x = (unsigned short)f2bf(kv.x); o.y = (unsigned short)f2bf(kv.y);
        o.z = (unsigned short)f2bf(kv.z); o.w = (unsigned short)f2bf(kv.w);
        *(ushort4*)(Kdst + (size_t)f4 * 4) = o;
    }
    const int key   = tid & 63;
    const int dbase = (tid >> 6) * 4;
    #pragma unroll
    for (int j = 0; j < 8; ++j) {
        const int d0 = dbase + j * 16;
        const float4 vv = *(const float4*)(Vsrc + (size_t)key * DH + d0);
        Vdst[(size_t)(d0 + 0) * SEQ + key] = (unsigned short)f2bf(vv.x);
        Vdst[(size_t)(d0 + 1) * SEQ + key] = (unsigned short)f2bf(vv.y);
        Vdst[(size_t)(d0 + 2) * SEQ + key] = (unsigned short)f2bf(vv.z);
        Vdst[(size_t)(d0 + 3) * SEQ + key] = (unsigned short)f2bf(vv.w);
    }
}

#define LOADK4(K0, K1, K2, K3, KEYBASE) do {                                   \
    const unsigned short* kr_ = Kbh + (size_t)((KEYBASE) + c16) * DH + g * 8;  \
    K0 = *(const bf16x8*)(kr_);                                                \
    K1 = *(const bf16x8*)(kr_ + 32);                                           \
    K2 = *(const bf16x8*)(kr_ + 64);                                           \
    K3 = *(const bf16x8*)(kr_ + 96);                                           \
} while (0)

// single-sweep QK tile: MFMA -> exp (unnormalized) -> accumulate rowsum + strip write
#define SW1(K0, K1, K2, K3, KEYBASE) do {                                      \
    f32x4 acc_ = {0.f, 0.f, 0.f, 0.f};                                         \
    acc_ = __builtin_amdgcn_mfma_f32_16x16x32_bf16(qf[0], K0, acc_, 0, 0, 0);  \
    acc_ = __builtin_amdgcn_mfma_f32_16x16x32_bf16(qf[1], K1, acc_, 0, 0, 0);  \
    acc_ = __builtin_amdgcn_mfma_f32_16x16x32_bf16(qf[2], K2, acc_, 0, 0, 0);  \
    acc_ = __builtin_amdgcn_mfma_f32_16x16x32_bf16(qf[3], K3, acc_, 0, 0, 0);  \
    const int key_ = (KEYBASE) + c16;                                          \
    const int qr_  = qw + g * 4;                                               \
    const float p0_ = (key_ <= qr_ + 0) ? __expf(acc_[0]) : 0.f;               \
    const float p1_ = (key_ <= qr_ + 1) ? __expf(acc_[1]) : 0.f;               \
    const float p2_ = (key_ <= qr_ + 2) ? __expf(acc_[2]) : 0.f;               \
    const float p3_ = (key_ <= qr_ + 3) ? __expf(acc_[3]) : 0.f;               \
    lsr[0] += p0_; lsr[1] += p1_; lsr[2] += p2_; lsr[3] += p3_;                \
    unsigned short* pq_ = &strip[g * 4][0] + key_;                             \
    pq_[0]        = (unsigned short)f2bf(p0_);                                 \
    pq_[PSTR]     = (unsigned short)f2bf(p1_);                                 \
    pq_[2 * PSTR] = (unsigned short)f2bf(p2_);                                 \
    pq_[3 * PSTR] = (unsigned short)f2bf(p3_);                                 \
} while (0)

#define LOADV8(V0,V1,V2,V3,V4,V5,V6,V7, KEYOFF) do {                           \
    const unsigned short* vb_ = Vbh + (size_t)c16 * SEQ + (KEYOFF) + g * 8;    \
    V0 = *(const bf16x8*)(vb_);                                                \
    V1 = *(const bf16x8*)(vb_ + 16 * SEQ);                                     \
    V2 = *(const bf16x8*)(vb_ + 32 * SEQ);                                     \
    V3 = *(const bf16x8*)(vb_ + 48 * SEQ);                                     \
    V4 = *(const bf16x8*)(vb_ + 64 * SEQ);                                     \
    V5 = *(const bf16x8*)(vb_ + 80 * SEQ);                                     \
    V6 = *(const bf16x8*)(vb_ + 96 * SEQ);                                     \
    V7 = *(const bf16x8*)(vb_ + 112 * SEQ);                                    \
} while (0)

#define PV8(PA, V0,V1,V2,V3,V4,V5,V6,V7) do {                                  \
    oacc[0] = __builtin_amdgcn_mfma_f32_16x16x32_bf16(PA, V0, oacc[0], 0, 0, 0); \
    oacc[1] = __builtin_amdgcn_mfma_f32_16x16x32_bf16(PA, V1, oacc[1], 0, 0, 0); \
    oacc[2] = __builtin_amdgcn_mfma_f32_16x16x32_bf16(PA, V2, oacc[2], 0, 0, 0); \
    oacc[3] = __builtin_amdgcn_mfma_f32_16x16x32_bf16(PA, V3, oacc[3], 0, 0, 0); \
    oacc[4] = __builtin_amdgcn_mfma_f32_16x16x32_bf16(PA, V4, oacc[4], 0, 0, 0); \
    oacc[5] = __builtin_amdgcn_mfma_f32_16x16x32_bf16(PA, V5, oacc[5], 0, 0, 0); \
    oacc[6] = __builtin_amdgcn_mfma_f32_16x16x32_bf16(PA, V6, oacc[6], 0, 0, 0); \
    oacc[7] = __builtin_amdgcn_mfma_f32_16x16x32_bf16(PA, V7, oacc[7], 0, 0, 0); \
} while (0)

// ---------- main: round-19 configuration (best measured: 164.0 us) ----------
// Single K sweep -> unnormalized P' in a 16x2048 bf16 LDS strip + rowsums;
// PV-only sweep 2 (no stores in the vmcnt stream); separate NT store pass
// (full rows, tail zeros merged); serial O-reduce; b%8 XCD mapping (validated
// by FETCH: 38->16 MB) + LPT qt order.
__global__ __launch_bounds__(512, 4) void attn_main(
    const float* __restrict__ qp, const unsigned short* __restrict__ Kb,
    const unsigned short* __restrict__ Vt, float* __restrict__ outO,
    float* __restrict__ outA)
{
    __shared__ float lspart[8][16];
    __shared__ float lrec[16];
    __shared__ float Osh[16][132];
    __shared__ __align__(16) unsigned short strip[16][PSTR];   // 65,792 B

    const int b   = blockIdx.x;            // 0..2047
    const int j   = b & 7;                 // XCD (validated: FETCH 38MB w/, 68MB w/o)
    const int idx = b >> 3;                // 0..255
    const int bh  = 2 * j + (idx & 1);
    const int qt  = 127 - (idx >> 1);      // heavy first (LPT)
    const int qw  = qt * 16;
    const size_t qbase = (size_t)bh * SEQ + qw;

    const int tid  = threadIdx.x;
    const int wv   = tid >> 6;
    const int lane = tid & 63;
    const int c16  = lane & 15;
    const int g    = lane >> 4;
    const float invT = 0.08838834764831845f;   // 1/sqrt(128)

    const unsigned short* Kbh = Kb + (size_t)bh * SEQ * DH;
    const unsigned short* Vbh = Vt + (size_t)bh * DH * SEQ;

    // ---- Q fragments: A[row=c16][k=32c+8g+j], pre-scaled ----
    bf16x8 qf[4];
    {
        const float* qrow = qp + (qbase + c16) * DH + g * 8;
        #pragma unroll
        for (int c = 0; c < 4; ++c) {
            const float4 a = *(const float4*)(qrow + c * 32);
            const float4 bq = *(const float4*)(qrow + c * 32 + 4);
            bf16x8 f;
            f[0] = f2bf(a.x * invT);  f[1] = f2bf(a.y * invT);
            f[2] = f2bf(a.z * invT);  f[3] = f2bf(a.w * invT);
            f[4] = f2bf(bq.x * invT); f[5] = f2bf(bq.y * invT);
            f[6] = f2bf(bq.z * invT); f[7] = f2bf(bq.w * invT);
            qf[c] = f;
        }
    }

    // ---- sweep 1: QK^T once, P' -> strip, rowsums; stride-8 interleave, 2-deep ----
    float lsr[4] = {0.f, 0.f, 0.f, 0.f};
    const int n16 = qt + 1;
    {
        bf16x8 ka0, ka1, ka2, ka3, kb0, kb1, kb2, kb3;
        int t = wv;
        if (t < n16) LOADK4(ka0, ka1, ka2, ka3, t << 4);
        for (; t + 8 < n16; t += 16) {
            LOADK4(kb0, kb1, kb2, kb3, (t + 8) << 4);
            SW1(ka0, ka1, ka2, ka3, t << 4);
            if (t + 16 < n16) LOADK4(ka0, ka1, ka2, ka3, (t + 16) << 4);
            SW1(kb0, kb1, kb2, kb3, (t + 8) << 4);
        }
        if (t < n16) SW1(ka0, ka1, ka2, ka3, t << 4);
    }
    #pragma unroll
    for (int r = 0; r < 4; ++r) {
        float s = lsr[r];
        #pragma unroll
        for (int m = 1; m < 16; m <<= 1) s += __shfl_xor(s, m);
        lsr[r] = s;
    }
    if (c16 == 0) {
        #pragma unroll
        for (int r = 0; r < 4; ++r) lspart[wv][g * 4 + r] = lsr[r];
    }
    __syncthreads();
    float li[4];
    #pragma unroll
    for (int r = 0; r < 4; ++r) {
        float s = 0.f;
        #pragma unroll
        for (int w = 0; w < 8; ++w) s += lspart[w][g * 4 + r];
        li[r] = 1.f / s;
    }
    const int ns = (qw + 79) >> 6;        // 64-key super-tiles covering keys <= qw+15
    if (wv == 0 && c16 == 0) {
        #pragma unroll
        for (int r = 0; r < 4; ++r) lrec[g * 4 + r] = li[r];
    }
    // zero strip gap cols [n16*16, ns*64)
    {
        const int row = tid >> 5;
        for (int c = n16 * 16 + (tid & 31); c < ns * 64; c += 32) strip[row][c] = 0;
    }
    __syncthreads();

    // ---- sweep 2: PV ONLY (no stores in the vmcnt stream) ----
    f32x4 oacc[8];
    #pragma unroll
    for (int d = 0; d < 8; ++d) oacc[d] = (f32x4){0.f, 0.f, 0.f, 0.f};

    {
        bf16x8 va0, va1, va2, va3, va4, va5, va6, va7;
        bf16x8 vb0, vb1, vb2, vb3, vb4, vb5, vb6, vb7;
        for (int S = wv; S < ns; S += 8) {
            const int KB = S << 6;
            LOADV8(va0,va1,va2,va3,va4,va5,va6,va7, KB);
            LOADV8(vb0,vb1,vb2,vb3,vb4,vb5,vb6,vb7, KB + 32);
            {
                const bf16x8 pa = *(const bf16x8*)(&strip[c16][KB + g * 8]);
                PV8(pa, va0,va1,va2,va3,va4,va5,va6,va7);
            }
            {
                const bf16x8 pa = *(const bf16x8*)(&strip[c16][KB + 32 + g * 8]);
                PV8(pa, vb0,vb1,vb2,vb3,vb4,vb5,vb6,vb7);
            }
        }
    }

    // ---- store pass: each wave streams 2 whole rows [0, SEQ) with NT stores ----
    // (strip-sourced below ns*64, zeros beyond — tail fill merged; nothing ever
    // waits on these stores, so they drain at fill rate under the O-reduce)
    {
        const int valid = ns * 64;
        #pragma unroll
        for (int rr = 0; rr < 2; ++rr) {
            const int row = wv * 2 + rr;
            const float lr = lrec[row];
            float* orow = outA + (qbase + row) * SEQ;
            const unsigned short* srow = &strip[row][0];
            for (int c = lane * 4; c < SEQ; c += 256) {
                f32x4 w;
                if (c < valid) {
                    w[0] = bf2f(srow[c + 0]) * lr;
                    w[1] = bf2f(srow[c + 1]) * lr;
                    w[2] = bf2f(srow[c + 2]) * lr;
                    w[3] = bf2f(srow[c + 3]) * lr;
                } else {
                    w[0] = 0.f; w[1] = 0.f; w[2] = 0.f; w[3] = 0.f;
                }
                __builtin_nontemporal_store(w, (f32x4*)(orow + c));
            }
        }
    }

    // ---- O: scale by li, cross-wave reduce in LDS (serial) ----
    for (int wp = 0; wp < 8; ++wp) {
        if (wv == wp) {
            #pragma unroll
            for (int dt = 0; dt < 8; ++dt) {
                #pragma unroll
                for (int r = 0; r < 4; ++r) {
                    const float val = oacc[dt][r] * li[r];
                    if (wp == 0) Osh[g * 4 + r][dt * 16 + c16]  = val;
                    else         Osh[g * 4 + r][dt * 16 + c16] += val;
                }
            }
        }
        __syncthreads();
    }
    {
        const int r  = tid >> 5;
        const int d0 = (tid & 31) * 4;
        float4 o;
        o.x = Osh[r][d0 + 0]; o.y = Osh[r][d0 + 1];
        o.z = Osh[r][d0 + 2]; o.w = Osh[r][d0 + 3];
        *(float4*)(outO + (qbase + r) * DH + d0) = o;
    }
}

// ---------- fallback (used only if ws too small) ----------
__global__ __launch_bounds__(256) void attn_fallback(
    const float* __restrict__ qp, const float* __restrict__ kp,
    const float* __restrict__ vp, float* __restrict__ outO,
    float* __restrict__ outA)
{
    const int qt   = blockIdx.x;
    const int bh   = blockIdx.y;
    const int wv   = threadIdx.x >> 6;
    const int lane = threadIdx.x & 63;
    const int c16  = lane & 15;
    const int g    = lane >> 4;
    const int qw = qt * 64 + wv * 16;
    const size_t qbase = (size_t)bh * SEQ + qw;
    const float invT = 0.08838834764831845f;

    bf16x8 qf[4];
    {
        const float* qrow = qp + (qbase + c16) * DH + g * 8;
        #pragma unroll
        for (int c = 0; c < 4; ++c) {
            const float4 a = *(const float4*)(qrow + c * 32);
            const float4 bq = *(const float4*)(qrow + c * 32 + 4);
            bf16x8 f;
            f[0] = f2bf(a.x * invT);  f[1] = f2bf(a.y * invT);
            f[2] = f2bf(a.z * invT);  f[3] = f2bf(a.w * invT);
            f[4] = f2bf(bq.x * invT); f[5] = f2bf(bq.y * invT);
            f[6] = f2bf(bq.z * invT); f[7] = f2bf(bq.w * invT);
            qf[c] = f;
        }
    }
    const float* kbase = kp + (size_t)bh * SEQ * DH;
    const float* vbase = vp + (size_t)bh * SEQ * DH;

    float ls0 = 0.f, ls1 = 0.f, ls2 = 0.f, ls3 = 0.f;
    const int nkt16 = (qw + 16) >> 4;
    for (int t = 0; t < nkt16; ++t) {
        const int kb = t << 4;
        const float* krow = kbase + (size_t)(kb + c16) * DH + g * 8;
        f32x4 acc = {0.f, 0.f, 0.f, 0.f};
        #pragma unroll
        for (int c = 0; c < 4; ++c) {
            const float4 a = *(const float4*)(krow + c * 32);
            const float4 bq = *(const float4*)(krow + c * 32 + 4);
            bf16x8 f;
            f[0] = f2bf(a.x);  f[1] = f2bf(a.y);  f[2] = f2bf(a.z);  f[3] = f2bf(a.w);
            f[4] = f2bf(bq.x); f[5] = f2bf(bq.y); f[6] = f2bf(bq.z); f[7] = f2bf(bq.w);
            acc = __builtin_amdgcn_mfma_f32_16x16x32_bf16(qf[c], f, acc, 0, 0, 0);
        }
        const int key = kb + c16;
        const int qr  = qw + g * 4;
        if (key <= qr + 0) ls0 += __expf(acc[0]);
        if (key <= qr + 1) ls1 += __expf(acc[1]);
        if (key <= qr + 2) ls2 += __expf(acc[2]);
        if (key <= qr + 3) ls3 += __expf(acc[3]);
    }
    #pragma unroll
    for (int m = 1; m < 16; m <<= 1) {
        ls0 += __shfl_xor(ls0, m);
        ls1 += __shfl_xor(ls1, m);
        ls2 += __shfl_xor(ls2, m);
        ls3 += __shfl_xor(ls3, m);
    }
    const float li0 = 1.f / ls0, li1 = 1.f / ls1, li2 = 1.f / ls2, li3 = 1.f / ls3;

    __shared__ __align__(16) short ptileF[4][16][32];
    f32x4 oacc[8];
    #pragma unroll
    for (int d = 0; d < 8; ++d) oacc[d] = (f32x4){0.f, 0.f, 0.f, 0.f};

    const int n32 = (qw + 47) >> 5;
    for (int t = 0; t < n32; ++t) {
        const int kb32 = t << 5;
        #pragma unroll
        for (int h = 0; h < 2; ++h) {
            const int kb = kb32 + h * 16;
            const float* krow = kbase + (size_t)(kb + c16) * DH + g * 8;
            f32x4 acc = {0.f, 0.f, 0.f, 0.f};
            #pragma unroll
            for (int c = 0; c < 4; ++c) {
                const float4 a = *(const float4*)(krow + c * 32);
                const float4 bq = *(const float4*)(krow + c * 32 + 4);
                bf16x8 f;
                f[0] = f2bf(a.x);  f[1] = f2bf(a.y);  f[2] = f2bf(a.z);  f[3] = f2bf(a.w);
                f[4] = f2bf(bq.x); f[5] = f2bf(bq.y); f[6] = f2bf(bq.z); f[7] = f2bf(bq.w);
                acc = __builtin_amdgcn_mfma_f32_16x16x32_bf16(qf[c], f, acc, 0, 0, 0);
            }
            const int key = kb + c16;
            const int qr  = qw + g * 4;
            const float p0 = (key <= qr + 0) ? __expf(acc[0]) * li0 : 0.f;
            const float p1 = (key <= qr + 1) ? __expf(acc[1]) * li1 : 0.f;
            const float p2 = (key <= qr + 2) ? __expf(acc[2]) * li2 : 0.f;
            const float p3 = (key <= qr + 3) ? __expf(acc[3]) * li3 : 0.f;
            outA[(qbase + g * 4 + 0) * SEQ + kb + c16] = p0;
            outA[(qbase + g * 4 + 1) * SEQ + kb + c16] = p1;
            outA[(qbase + g * 4 + 2) * SEQ + kb + c16] = p2;
            outA[(qbase + g * 4 + 3) * SEQ + kb + c16] = p3;
            ptileF[wv][g * 4 + 0][h * 16 + c16] = f2bf(p0);
            ptileF[wv][g * 4 + 1][h * 16 + c16] = f2bf(p1);
            ptileF[wv][g * 4 + 2][h * 16 + c16] = f2bf(p2);
            ptileF[wv][g * 4 + 3][h * 16 + c16] = f2bf(p3);
        }
        bf16x8 pa = *(bf16x8*)&ptileF[wv][c16][g * 8];
        #pragma unroll
        for (int dt = 0; dt < 8; ++dt) {
            const float* vcol = vbase + (size_t)(kb32 + g * 8) * DH + dt * 16 + c16;
            bf16x8 vf;
            #pragma unroll
            for (int i = 0; i < 8; ++i) vf[i] = f2bf(vcol[(size_t)i * DH]);
            oacc[dt] = __builtin_amdgcn_mfma_f32_16x16x32_bf16(pa, vf, oacc[dt], 0, 0, 0);
        }
    }
    {
        const float4 z4 = {0.f, 0.f, 0.f, 0.f};
        float* zrow = outA + (qbase + (lane >> 2)) * SEQ;
        for (int c = n32 * 32 + (lane & 3) * 8; c < SEQ; c += 32) {
            *(float4*)(zrow + c)     = z4;
            *(float4*)(zrow + c + 4) = z4;
        }
    }
    #pragma unroll
    for (int dt = 0; dt < 8; ++dt) {
        #pragma unroll
        for (int r = 0; r < 4; ++r) {
            outO[(qbase + g * 4 + r) * DH + dt * 16 + c16] = oacc[dt][r];
        }
    }
}

extern "C" void kernel_launch(void* const* d_in, const int* in_sizes, int n_in,
                              void* d_out, int out_size, void* d_ws, size_t ws_size,
                              hipStream_t stream) {
    (void)in_sizes; (void)n_in; (void)out_size;
    const float* q = (const float*)d_in[0];
    const float* k = (const float*)d_in[1];
    const float* v = (const float*)d_in[2];
    float* outO = (float*)d_out;                   // [BH, S, D] f32
    float* outA = outO + (size_t)BH_N * SEQ * DH;  // [BH, S, S] f32

    const size_t need = (size_t)BH_N * SEQ * DH * sizeof(unsigned short) * 2;  // Kb + Vt
    if (ws_size >= need) {
        unsigned short* Kb = (unsigned short*)d_ws;
        unsigned short* Vt = Kb + (size_t)BH_N * SEQ * DH;
        prep_kv<<<dim3(SEQ / 64, BH_N), 256, 0, stream>>>(k, v, Kb, Vt);
        attn_main<<<dim3(2048), 512, 0, stream>>>(q, Kb, Vt, outO, outA);
    } else {
        attn_fallback<<<dim3(SEQ / 64, BH_N), 256, 0, stream>>>(q, k, v, outO, outA);
    }
}

// Round 22
// 161.850 us; speedup vs baseline: 1.0433x; 1.0146x over previous
//
#include <hip/hip_runtime.h>
#include <hip/hip_bf16.h>

#define BH_N 16
#define SEQ 2048
#define DH 128
#define PSTR 2056   // strip row stride in shorts (2048 + 8: keeps 16B row alignment)

typedef __attribute__((ext_vector_type(8))) short bf16x8;
typedef __attribute__((ext_vector_type(4))) float f32x4;

__device__ __forceinline__ short f2bf(float x) {
    union { __hip_bfloat16 b; short s; } u;
    u.b = __float2bfloat16(x);
    return u.s;
}
__device__ __forceinline__ float bf2f(unsigned short s) {
    union { unsigned int u; float f; } v;
    v.u = ((unsigned int)s) << 16;
    return v.f;
}

// ---------- prep: K -> bf16 [bh][key][d]; V -> bf16 transposed [bh][d][key] ----------
__global__ __launch_bounds__(256) void prep_kv(
    const float* __restrict__ kp, const float* __restrict__ vp,
    unsigned short* __restrict__ Kb, unsigned short* __restrict__ Vt)
{
    const int tid  = threadIdx.x;
    const int kb64 = blockIdx.x * 64;
    const int bh   = blockIdx.y;
    const float* Ksrc = kp + ((size_t)bh * SEQ + kb64) * DH;
    const float* Vsrc = vp + ((size_t)bh * SEQ + kb64) * DH;
    unsigned short* Kdst = Kb + ((size_t)bh * SEQ + kb64) * DH;
    unsigned short* Vdst = Vt + (size_t)bh * DH * SEQ + kb64;

    #pragma unroll
    for (int i = 0; i < 8; ++i) {
        const int f4 = i * 256 + tid;
        const float4 kv = *(const float4*)(Ksrc + (size_t)f4 * 4);
        ushort4 o;
        o.x = (unsigned short)f2bf(kv.x); o.y = (unsigned short)f2bf(kv.y);
        o.z = (unsigned short)f2bf(kv.z); o.w = (unsigned short)f2bf(kv.w);
        *(ushort4*)(Kdst + (size_t)f4 * 4) = o;
    }
    const int key   = tid & 63;
    const int dbase = (tid >> 6) * 4;
    #pragma unroll
    for (int j = 0; j < 8; ++j) {
        const int d0 = dbase + j * 16;
        const float4 vv = *(const float4*)(Vsrc + (size_t)key * DH + d0);
        Vdst[(size_t)(d0 + 0) * SEQ + key] = (unsigned short)f2bf(vv.x);
        Vdst[(size_t)(d0 + 1) * SEQ + key] = (unsigned short)f2bf(vv.y);
        Vdst[(size_t)(d0 + 2) * SEQ + key] = (unsigned short)f2bf(vv.z);
        Vdst[(size_t)(d0 + 3) * SEQ + key] = (unsigned short)f2bf(vv.w);
    }
}

#define LOADK4(K0, K1, K2, K3, KEYBASE) do {                                   \
    const unsigned short* kr_ = Kbh + (size_t)((KEYBASE) + c16) * DH + g * 8;  \
    K0 = *(const bf16x8*)(kr_);                                                \
    K1 = *(const bf16x8*)(kr_ + 32);                                           \
    K2 = *(const bf16x8*)(kr_ + 64);                                           \
    K3 = *(const bf16x8*)(kr_ + 96);                                           \
} while (0)

// single-sweep QK tile: MFMA (setprio-wrapped) -> exp (unnormalized) -> rowsum + strip
#define SW1(K0, K1, K2, K3, KEYBASE) do {                                      \
    f32x4 acc_ = {0.f, 0.f, 0.f, 0.f};                                         \
    __builtin_amdgcn_s_setprio(1);                                             \
    acc_ = __builtin_amdgcn_mfma_f32_16x16x32_bf16(qf[0], K0, acc_, 0, 0, 0);  \
    acc_ = __builtin_amdgcn_mfma_f32_16x16x32_bf16(qf[1], K1, acc_, 0, 0, 0);  \
    acc_ = __builtin_amdgcn_mfma_f32_16x16x32_bf16(qf[2], K2, acc_, 0, 0, 0);  \
    acc_ = __builtin_amdgcn_mfma_f32_16x16x32_bf16(qf[3], K3, acc_, 0, 0, 0);  \
    __builtin_amdgcn_s_setprio(0);                                             \
    const int key_ = (KEYBASE) + c16;                                          \
    const int qr_  = qw + g * 4;                                               \
    const float p0_ = (key_ <= qr_ + 0) ? __expf(acc_[0]) : 0.f;               \
    const float p1_ = (key_ <= qr_ + 1) ? __expf(acc_[1]) : 0.f;               \
    const float p2_ = (key_ <= qr_ + 2) ? __expf(acc_[2]) : 0.f;               \
    const float p3_ = (key_ <= qr_ + 3) ? __expf(acc_[3]) : 0.f;               \
    lsr[0] += p0_; lsr[1] += p1_; lsr[2] += p2_; lsr[3] += p3_;                \
    unsigned short* pq_ = &strip[g * 4][0] + key_;                             \
    pq_[0]        = (unsigned short)f2bf(p0_);                                 \
    pq_[PSTR]     = (unsigned short)f2bf(p1_);                                 \
    pq_[2 * PSTR] = (unsigned short)f2bf(p2_);                                 \
    pq_[3 * PSTR] = (unsigned short)f2bf(p3_);                                 \
} while (0)

#define LOADV8(V0,V1,V2,V3,V4,V5,V6,V7, KEYOFF) do {                           \
    const unsigned short* vb_ = Vbh + (size_t)c16 * SEQ + (KEYOFF) + g * 8;    \
    V0 = *(const bf16x8*)(vb_);                                                \
    V1 = *(const bf16x8*)(vb_ + 16 * SEQ);                                     \
    V2 = *(const bf16x8*)(vb_ + 32 * SEQ);                                     \
    V3 = *(const bf16x8*)(vb_ + 48 * SEQ);                                     \
    V4 = *(const bf16x8*)(vb_ + 64 * SEQ);                                     \
    V5 = *(const bf16x8*)(vb_ + 80 * SEQ);                                     \
    V6 = *(const bf16x8*)(vb_ + 96 * SEQ);                                     \
    V7 = *(const bf16x8*)(vb_ + 112 * SEQ);                                    \
} while (0)

#define PV8(PA, V0,V1,V2,V3,V4,V5,V6,V7) do {                                  \
    __builtin_amdgcn_s_setprio(1);                                             \
    oacc[0] = __builtin_amdgcn_mfma_f32_16x16x32_bf16(PA, V0, oacc[0], 0, 0, 0); \
    oacc[1] = __builtin_amdgcn_mfma_f32_16x16x32_bf16(PA, V1, oacc[1], 0, 0, 0); \
    oacc[2] = __builtin_amdgcn_mfma_f32_16x16x32_bf16(PA, V2, oacc[2], 0, 0, 0); \
    oacc[3] = __builtin_amdgcn_mfma_f32_16x16x32_bf16(PA, V3, oacc[3], 0, 0, 0); \
    oacc[4] = __builtin_amdgcn_mfma_f32_16x16x32_bf16(PA, V4, oacc[4], 0, 0, 0); \
    oacc[5] = __builtin_amdgcn_mfma_f32_16x16x32_bf16(PA, V5, oacc[5], 0, 0, 0); \
    oacc[6] = __builtin_amdgcn_mfma_f32_16x16x32_bf16(PA, V6, oacc[6], 0, 0, 0); \
    oacc[7] = __builtin_amdgcn_mfma_f32_16x16x32_bf16(PA, V7, oacc[7], 0, 0, 0); \
    __builtin_amdgcn_s_setprio(0);                                             \
} while (0)

// ---------- main: round-19 configuration + setprio(MFMA) + vectorized strip reads ----
// Single K sweep -> unnormalized P' in a 16x2048 bf16 LDS strip + rowsums;
// PV-only sweep 2; separate NT store pass (full rows, tail zeros merged);
// serial O-reduce; b%8 XCD mapping (validated by FETCH 38->16 MB) + LPT order.
__global__ __launch_bounds__(512, 4) void attn_main(
    const float* __restrict__ qp, const unsigned short* __restrict__ Kb,
    const unsigned short* __restrict__ Vt, float* __restrict__ outO,
    float* __restrict__ outA)
{
    __shared__ float lspart[8][16];
    __shared__ float lrec[16];
    __shared__ float Osh[16][132];
    __shared__ __align__(16) unsigned short strip[16][PSTR];   // 65,792 B

    const int b   = blockIdx.x;            // 0..2047
    const int j   = b & 7;                 // XCD (validated: FETCH 38MB w/, 68MB w/o)
    const int idx = b >> 3;                // 0..255
    const int bh  = 2 * j + (idx & 1);
    const int qt  = 127 - (idx >> 1);      // heavy first (LPT)
    const int qw  = qt * 16;
    const size_t qbase = (size_t)bh * SEQ + qw;

    const int tid  = threadIdx.x;
    const int wv   = tid >> 6;
    const int lane = tid & 63;
    const int c16  = lane & 15;
    const int g    = lane >> 4;
    const float invT = 0.08838834764831845f;   // 1/sqrt(128)

    const unsigned short* Kbh = Kb + (size_t)bh * SEQ * DH;
    const unsigned short* Vbh = Vt + (size_t)bh * DH * SEQ;

    // ---- Q fragments: A[row=c16][k=32c+8g+j], pre-scaled ----
    bf16x8 qf[4];
    {
        const float* qrow = qp + (qbase + c16) * DH + g * 8;
        #pragma unroll
        for (int c = 0; c < 4; ++c) {
            const float4 a = *(const float4*)(qrow + c * 32);
            const float4 bq = *(const float4*)(qrow + c * 32 + 4);
            bf16x8 f;
            f[0] = f2bf(a.x * invT);  f[1] = f2bf(a.y * invT);
            f[2] = f2bf(a.z * invT);  f[3] = f2bf(a.w * invT);
            f[4] = f2bf(bq.x * invT); f[5] = f2bf(bq.y * invT);
            f[6] = f2bf(bq.z * invT); f[7] = f2bf(bq.w * invT);
            qf[c] = f;
        }
    }

    // ---- sweep 1: QK^T once, P' -> strip, rowsums; stride-8 interleave, 2-deep ----
    float lsr[4] = {0.f, 0.f, 0.f, 0.f};
    const int n16 = qt + 1;
    {
        bf16x8 ka0, ka1, ka2, ka3, kb0, kb1, kb2, kb3;
        int t = wv;
        if (t < n16) LOADK4(ka0, ka1, ka2, ka3, t << 4);
        for (; t + 8 < n16; t += 16) {
            LOADK4(kb0, kb1, kb2, kb3, (t + 8) << 4);
            SW1(ka0, ka1, ka2, ka3, t << 4);
            if (t + 16 < n16) LOADK4(ka0, ka1, ka2, ka3, (t + 16) << 4);
            SW1(kb0, kb1, kb2, kb3, (t + 8) << 4);
        }
        if (t < n16) SW1(ka0, ka1, ka2, ka3, t << 4);
    }
    #pragma unroll
    for (int r = 0; r < 4; ++r) {
        float s = lsr[r];
        #pragma unroll
        for (int m = 1; m < 16; m <<= 1) s += __shfl_xor(s, m);
        lsr[r] = s;
    }
    if (c16 == 0) {
        #pragma unroll
        for (int r = 0; r < 4; ++r) lspart[wv][g * 4 + r] = lsr[r];
    }
    __syncthreads();
    float li[4];
    #pragma unroll
    for (int r = 0; r < 4; ++r) {
        float s = 0.f;
        #pragma unroll
        for (int w = 0; w < 8; ++w) s += lspart[w][g * 4 + r];
        li[r] = 1.f / s;
    }
    const int ns = (qw + 79) >> 6;        // 64-key super-tiles covering keys <= qw+15
    if (wv == 0 && c16 == 0) {
        #pragma unroll
        for (int r = 0; r < 4; ++r) lrec[g * 4 + r] = li[r];
    }
    // zero strip gap cols [n16*16, ns*64)
    {
        const int row = tid >> 5;
        for (int c = n16 * 16 + (tid & 31); c < ns * 64; c += 32) strip[row][c] = 0;
    }
    __syncthreads();

    // ---- sweep 2: PV ONLY (no stores in the vmcnt stream) ----
    f32x4 oacc[8];
    #pragma unroll
    for (int d = 0; d < 8; ++d) oacc[d] = (f32x4){0.f, 0.f, 0.f, 0.f};

    {
        bf16x8 va0, va1, va2, va3, va4, va5, va6, va7;
        bf16x8 vb0, vb1, vb2, vb3, vb4, vb5, vb6, vb7;
        for (int S = wv; S < ns; S += 8) {
            const int KB = S << 6;
            LOADV8(va0,va1,va2,va3,va4,va5,va6,va7, KB);
            LOADV8(vb0,vb1,vb2,vb3,vb4,vb5,vb6,vb7, KB + 32);
            {
                const bf16x8 pa = *(const bf16x8*)(&strip[c16][KB + g * 8]);
                PV8(pa, va0,va1,va2,va3,va4,va5,va6,va7);
            }
            {
                const bf16x8 pa = *(const bf16x8*)(&strip[c16][KB + 32 + g * 8]);
                PV8(pa, vb0,vb1,vb2,vb3,vb4,vb5,vb6,vb7);
            }
        }
    }

    // ---- store pass: each wave streams 2 whole rows [0, SEQ) with NT stores ----
    // (strip-sourced below ns*64 via vector b64 LDS reads, zeros beyond — tail
    // fill merged; nothing ever waits on these stores)
    {
        const int valid = ns * 64;
        #pragma unroll
        for (int rr = 0; rr < 2; ++rr) {
            const int row = wv * 2 + rr;
            const float lr = lrec[row];
            float* orow = outA + (qbase + row) * SEQ;
            const unsigned short* srow = &strip[row][0];
            for (int c = lane * 4; c < SEQ; c += 256) {
                f32x4 w;
                if (c < valid) {
                    const ushort4 s4 = *(const ushort4*)(srow + c);   // one b64 read
                    w[0] = bf2f(s4.x) * lr;
                    w[1] = bf2f(s4.y) * lr;
                    w[2] = bf2f(s4.z) * lr;
                    w[3] = bf2f(s4.w) * lr;
                } else {
                    w[0] = 0.f; w[1] = 0.f; w[2] = 0.f; w[3] = 0.f;
                }
                __builtin_nontemporal_store(w, (f32x4*)(orow + c));
            }
        }
    }

    // ---- O: scale by li, cross-wave reduce in LDS (serial) ----
    for (int wp = 0; wp < 8; ++wp) {
        if (wv == wp) {
            #pragma unroll
            for (int dt = 0; dt < 8; ++dt) {
                #pragma unroll
                for (int r = 0; r < 4; ++r) {
                    const float val = oacc[dt][r] * li[r];
                    if (wp == 0) Osh[g * 4 + r][dt * 16 + c16]  = val;
                    else         Osh[g * 4 + r][dt * 16 + c16] += val;
                }
            }
        }
        __syncthreads();
    }
    {
        const int r  = tid >> 5;
        const int d0 = (tid & 31) * 4;
        float4 o;
        o.x = Osh[r][d0 + 0]; o.y = Osh[r][d0 + 1];
        o.z = Osh[r][d0 + 2]; o.w = Osh[r][d0 + 3];
        *(float4*)(outO + (qbase + r) * DH + d0) = o;
    }
}

// ---------- fallback (used only if ws too small) ----------
__global__ __launch_bounds__(256) void attn_fallback(
    const float* __restrict__ qp, const float* __restrict__ kp,
    const float* __restrict__ vp, float* __restrict__ outO,
    float* __restrict__ outA)
{
    const int qt   = blockIdx.x;
    const int bh   = blockIdx.y;
    const int wv   = threadIdx.x >> 6;
    const int lane = threadIdx.x & 63;
    const int c16  = lane & 15;
    const int g    = lane >> 4;
    const int qw = qt * 64 + wv * 16;
    const size_t qbase = (size_t)bh * SEQ + qw;
    const float invT = 0.08838834764831845f;

    bf16x8 qf[4];
    {
        const float* qrow = qp + (qbase + c16) * DH + g * 8;
        #pragma unroll
        for (int c = 0; c < 4; ++c) {
            const float4 a = *(const float4*)(qrow + c * 32);
            const float4 bq = *(const float4*)(qrow + c * 32 + 4);
            bf16x8 f;
            f[0] = f2bf(a.x * invT);  f[1] = f2bf(a.y * invT);
            f[2] = f2bf(a.z * invT);  f[3] = f2bf(a.w * invT);
            f[4] = f2bf(bq.x * invT); f[5] = f2bf(bq.y * invT);
            f[6] = f2bf(bq.z * invT); f[7] = f2bf(bq.w * invT);
            qf[c] = f;
        }
    }
    const float* kbase = kp + (size_t)bh * SEQ * DH;
    const float* vbase = vp + (size_t)bh * SEQ * DH;

    float ls0 = 0.f, ls1 = 0.f, ls2 = 0.f, ls3 = 0.f;
    const int nkt16 = (qw + 16) >> 4;
    for (int t = 0; t < nkt16; ++t) {
        const int kb = t << 4;
        const float* krow = kbase + (size_t)(kb + c16) * DH + g * 8;
        f32x4 acc = {0.f, 0.f, 0.f, 0.f};
        #pragma unroll
        for (int c = 0; c < 4; ++c) {
            const float4 a = *(const float4*)(krow + c * 32);
            const float4 bq = *(const float4*)(krow + c * 32 + 4);
            bf16x8 f;
            f[0] = f2bf(a.x);  f[1] = f2bf(a.y);  f[2] = f2bf(a.z);  f[3] = f2bf(a.w);
            f[4] = f2bf(bq.x); f[5] = f2bf(bq.y); f[6] = f2bf(bq.z); f[7] = f2bf(bq.w);
            acc = __builtin_amdgcn_mfma_f32_16x16x32_bf16(qf[c], f, acc, 0, 0, 0);
        }
        const int key = kb + c16;
        const int qr  = qw + g * 4;
        if (key <= qr + 0) ls0 += __expf(acc[0]);
        if (key <= qr + 1) ls1 += __expf(acc[1]);
        if (key <= qr + 2) ls2 += __expf(acc[2]);
        if (key <= qr + 3) ls3 += __expf(acc[3]);
    }
    #pragma unroll
    for (int m = 1; m < 16; m <<= 1) {
        ls0 += __shfl_xor(ls0, m);
        ls1 += __shfl_xor(ls1, m);
        ls2 += __shfl_xor(ls2, m);
        ls3 += __shfl_xor(ls3, m);
    }
    const float li0 = 1.f / ls0, li1 = 1.f / ls1, li2 = 1.f / ls2, li3 = 1.f / ls3;

    __shared__ __align__(16) short ptileF[4][16][32];
    f32x4 oacc[8];
    #pragma unroll
    for (int d = 0; d < 8; ++d) oacc[d] = (f32x4){0.f, 0.f, 0.f, 0.f};

    const int n32 = (qw + 47) >> 5;
    for (int t = 0; t < n32; ++t) {
        const int kb32 = t << 5;
        #pragma unroll
        for (int h = 0; h < 2; ++h) {
            const int kb = kb32 + h * 16;
            const float* krow = kbase + (size_t)(kb + c16) * DH + g * 8;
            f32x4 acc = {0.f, 0.f, 0.f, 0.f};
            #pragma unroll
            for (int c = 0; c < 4; ++c) {
                const float4 a = *(const float4*)(krow + c * 32);
                const float4 bq = *(const float4*)(krow + c * 32 + 4);
                bf16x8 f;
                f[0] = f2bf(a.x);  f[1] = f2bf(a.y);  f[2] = f2bf(a.z);  f[3] = f2bf(a.w);
                f[4] = f2bf(bq.x); f[5] = f2bf(bq.y); f[6] = f2bf(bq.z); f[7] = f2bf(bq.w);
                acc = __builtin_amdgcn_mfma_f32_16x16x32_bf16(qf[c], f, acc, 0, 0, 0);
            }
            const int key = kb + c16;
            const int qr  = qw + g * 4;
            const float p0 = (key <= qr + 0) ? __expf(acc[0]) * li0 : 0.f;
            const float p1 = (key <= qr + 1) ? __expf(acc[1]) * li1 : 0.f;
            const float p2 = (key <= qr + 2) ? __expf(acc[2]) * li2 : 0.f;
            const float p3 = (key <= qr + 3) ? __expf(acc[3]) * li3 : 0.f;
            outA[(qbase + g * 4 + 0) * SEQ + kb + c16] = p0;
            outA[(qbase + g * 4 + 1) * SEQ + kb + c16] = p1;
            outA[(qbase + g * 4 + 2) * SEQ + kb + c16] = p2;
            outA[(qbase + g * 4 + 3) * SEQ + kb + c16] = p3;
            ptileF[wv][g * 4 + 0][h * 16 + c16] = f2bf(p0);
            ptileF[wv][g * 4 + 1][h * 16 + c16] = f2bf(p1);
            ptileF[wv][g * 4 + 2][h * 16 + c16] = f2bf(p2);
            ptileF[wv][g * 4 + 3][h * 16 + c16] = f2bf(p3);
        }
        bf16x8 pa = *(bf16x8*)&ptileF[wv][c16][g * 8];
        #pragma unroll
        for (int dt = 0; dt < 8; ++dt) {
            const float* vcol = vbase + (size_t)(kb32 + g * 8) * DH + dt * 16 + c16;
            bf16x8 vf;
            #pragma unroll
            for (int i = 0; i < 8; ++i) vf[i] = f2bf(vcol[(size_t)i * DH]);
            oacc[dt] = __builtin_amdgcn_mfma_f32_16x16x32_bf16(pa, vf, oacc[dt], 0, 0, 0);
        }
    }
    {
        const float4 z4 = {0.f, 0.f, 0.f, 0.f};
        float* zrow = outA + (qbase + (lane >> 2)) * SEQ;
        for (int c = n32 * 32 + (lane & 3) * 8; c < SEQ; c += 32) {
            *(float4*)(zrow + c)     = z4;
            *(float4*)(zrow + c + 4) = z4;
        }
    }
    #pragma unroll
    for (int dt = 0; dt < 8; ++dt) {
        #pragma unroll
        for (int r = 0; r < 4; ++r) {
            outO[(qbase + g * 4 + r) * DH + dt * 16 + c16] = oacc[dt][r];
        }
    }
}

extern "C" void kernel_launch(void* const* d_in, const int* in_sizes, int n_in,
                              void* d_out, int out_size, void* d_ws, size_t ws_size,
                              hipStream_t stream) {
    (void)in_sizes; (void)n_in; (void)out_size;
    const float* q = (const float*)d_in[0];
    const float* k = (const float*)d_in[1];
    const float* v = (const float*)d_in[2];
    float* outO = (float*)d_out;                   // [BH, S, D] f32
    float* outA = outO + (size_t)BH_N * SEQ * DH;  // [BH, S, S] f32

    const size_t need = (size_t)BH_N * SEQ * DH * sizeof(unsigned short) * 2;  // Kb + Vt
    if (ws_size >= need) {
        unsigned short* Kb = (unsigned short*)d_ws;
        unsigned short* Vt = Kb + (size_t)BH_N * SEQ * DH;
        prep_kv<<<dim3(SEQ / 64, BH_N), 256, 0, stream>>>(k, v, Kb, Vt);
        attn_main<<<dim3(2048), 512, 0, stream>>>(q, Kb, Vt, outO, outA);
    } else {
        attn_fallback<<<dim3(SEQ / 64, BH_N), 256, 0, stream>>>(q, k, v, outO, outA);
    }
}